// Round 2
// baseline (246.112 us; speedup 1.0000x reference)
//
#include <hip/hip_runtime.h>

// out[b,o,i,j] = sum_c | sum_{ti,tj} K[o,0,ti,tj] * x[b,c,(i+5-ti)&127,(j+5-tj)&127] |
// B=8 C=16 H=W=128 O=32 KS=9. Derived from the FFT reference:
// fftshift/ifftshift cancel for even N; real*real => field is real => abs = fabsf.
//
// R1: c-split x2 (8 ch/block, fp32 atomic combine) -> 1024 blocks = 4/CU.
//     LDS stride 72 -> 76 to break bank-conflict phase. launch_bounds(256,4).

#define B_ 8
#define C_ 16
#define H_ 128
#define O_ 32
#define TH 16   // output rows per block
#define TW 64   // output cols per block (16 threads x 4 px)
#define GO 8    // output channels per block
#define LR 24   // TH + 8 halo rows (i-3..i+5)
#define LC 76   // TW + 8 halo cols + 4 pad (bank-quad stride 19 mod 8 = 3)

__global__ __launch_bounds__(256, 4)
void optical_conv_69698729279498(const float* __restrict__ x,
                                 const float* __restrict__ kern,
                                 float* __restrict__ out) {
    __shared__ __align__(16) float lds[LR * LC];  // 1824 floats = 7.1 KB

    const int tx = threadIdx.x;              // 0..15 -> 4 cols each
    const int ty = threadIdx.y;              // 0..15 -> row
    const int tid = ty * 16 + tx;
    const int og = blockIdx.x & 3;           // o-group 0..3
    const int cs = blockIdx.x >> 2;          // c-split 0..1
    const int tile = blockIdx.y;             // 0..15 spatial tile
    const int b = blockIdx.z;                // 0..7
    const int c0 = (tile & 1) * TW;
    const int r0 = (tile >> 1) * TH;
    const int obase = og * GO;
    const int cbeg = cs * 8;

    float acc[GO][4];
#pragma unroll
    for (int o = 0; o < GO; ++o)
#pragma unroll
        for (int p = 0; p < 4; ++p) acc[o][p] = 0.f;

    for (int cc8 = 0; cc8 < 8; ++cc8) {
        const int c = cbeg + cc8;
        __syncthreads();  // protect LDS from previous iteration's readers
        // stage 24x76 halo tile (circular wrap via &127)
        const float* xc = x + ((size_t)(b * C_ + c)) * H_ * H_;
        for (int idx = tid; idx < LR * LC; idx += 256) {
            int rr = idx / LC;
            int cc = idx - rr * LC;
            int gr = (r0 - 3 + rr) & 127;
            int gc = (c0 - 3 + cc) & 127;
            lds[idx] = xc[(gr << 7) + gc];
        }
        __syncthreads();

        float f[GO][4];
#pragma unroll
        for (int o = 0; o < GO; ++o)
#pragma unroll
            for (int p = 0; p < 4; ++p) f[o][p] = 0.f;

        for (int ti = 0; ti < 9; ++ti) {
            // output row i=r0+ty needs lds row ty+8-ti,
            // cols 4tx + (p+8-tj), p in [0,4), tj in [0,9) -> 12 floats
            const float4* wp = (const float4*)&lds[(ty + 8 - ti) * LC + 4 * tx];
            float4 w0 = wp[0], w1 = wp[1], w2 = wp[2];
            float xw[12] = {w0.x, w0.y, w0.z, w0.w,
                            w1.x, w1.y, w1.z, w1.w,
                            w2.x, w2.y, w2.z, w2.w};
            const float* kbase = kern + ti * 9;   // kernel[o,0,ti,tj]
#pragma unroll
            for (int o = 0; o < GO; ++o) {
                const float* kp = kbase + (obase + o) * (C_ * 81);
#pragma unroll
                for (int tj = 0; tj < 9; ++tj) {
                    float kv = kp[tj];  // wave-uniform -> s_load
#pragma unroll
                    for (int p = 0; p < 4; ++p)
                        f[o][p] = fmaf(xw[p + 8 - tj], kv, f[o][p]);
                }
            }
        }
#pragma unroll
        for (int o = 0; o < GO; ++o)
#pragma unroll
            for (int p = 0; p < 4; ++p) acc[o][p] += fabsf(f[o][p]);
    }

    const int orow = r0 + ty;
    const int ocol = c0 + 4 * tx;
#pragma unroll
    for (int o = 0; o < GO; ++o) {
        float* op = &out[((size_t)((b * O_) + obase + o) * H_ + orow) * H_ + ocol];
#pragma unroll
        for (int p = 0; p < 4; ++p)
            unsafeAtomicAdd(op + p, acc[o][p]);  // native global_atomic_add_f32
    }
}

extern "C" void kernel_launch(void* const* d_in, const int* in_sizes, int n_in,
                              void* d_out, int out_size, void* d_ws, size_t ws_size,
                              hipStream_t stream) {
    const float* x = (const float*)d_in[0];      // [8,16,128,128]
    const float* kern = (const float*)d_in[1];   // [32,16,9,9]
    float* out = (float*)d_out;                  // [8,32,128,128]
    // harness poisons d_out before every launch; atomics need zero-init
    hipMemsetAsync(out, 0, (size_t)out_size * sizeof(float), stream);
    dim3 block(16, 16);
    dim3 grid(8, 16, 8);   // (o-group x c-split) x tiles x batch = 1024 blocks
    hipLaunchKernelGGL(optical_conv_69698729279498, grid, block, 0, stream,
                       x, kern, out);
}

// Round 3
// 110.546 us; speedup vs baseline: 2.2263x; 2.2263x over previous
//
#include <hip/hip_runtime.h>
#include <hip/hip_bf16.h>

// out[b,o,i,j] = sum_c | sum_{ti,tj<=8} K[o,0,ti,tj] * x[b,c,(i+5-ti)&127,(j+5-tj)&127] |
// B=8 C=16 H=W=128 O=32. MFMA im2col formulation:
//   per (b,c): D[m][o] = sum_k A[m][k]*Bk[k][o], k = ti*16+tj (tj pad 16, ti pad 10, K=160)
//   A[m][k] = x[i+5-ti][j+5-tj], j = 8*(m) + phase.  acc += |D| over c.
// LDS stores x row-halo COLUMN-REVERSED bf16: ldsb[r][cc] = x[(i-4+r)&127][(132-cc)&127]
// so lane A-frags are contiguous: cc = 127 - j + tj.  m-tile = 16 pixels stride 8
// -> all ds_read_b128 16B-aligned; one 32B window serves 4 phases via v_alignbit.

typedef __attribute__((ext_vector_type(8)))  short  short8;
typedef __attribute__((ext_vector_type(4)))  float  float4v;
typedef __attribute__((ext_vector_type(4)))  unsigned int uint4v;

#define NROW 10
#define NCC  144   // bf16 per LDS row = 288 B (row stride)

__device__ __forceinline__ unsigned short f2bf(float f) {
    union { float f; unsigned int u; } a; a.f = f;
    unsigned int u = a.u;
    u += 0x7fffu + ((u >> 16) & 1u);   // RNE
    return (unsigned short)(u >> 16);
}

// frag = 8 bf16 starting at bf16-offset (2q + odd) within window wnd[0..7]
#define MFMA_PHASE(q_, odd_, Dv_)                                            \
    {                                                                        \
        uint4v fr;                                                           \
        if (odd_) {                                                          \
            fr.x = (unsigned int)((((unsigned long long)wnd[(q_)+1] << 32) | wnd[(q_)+0]) >> 16); \
            fr.y = (unsigned int)((((unsigned long long)wnd[(q_)+2] << 32) | wnd[(q_)+1]) >> 16); \
            fr.z = (unsigned int)((((unsigned long long)wnd[(q_)+3] << 32) | wnd[(q_)+2]) >> 16); \
            fr.w = (unsigned int)((((unsigned long long)wnd[(q_)+4] << 32) | wnd[(q_)+3]) >> 16); \
        } else {                                                             \
            fr.x = wnd[(q_)+0]; fr.y = wnd[(q_)+1];                          \
            fr.z = wnd[(q_)+2]; fr.w = wnd[(q_)+3];                          \
        }                                                                    \
        short8 af = __builtin_bit_cast(short8, fr);                          \
        Dv_ = __builtin_amdgcn_mfma_f32_16x16x32_bf16(af, Bf[ch], Dv_, 0, 0, 0); \
    }

__global__ __launch_bounds__(256, 4)
void optical_conv_69698729279498(const float* __restrict__ x,
                                 const float* __restrict__ kern,
                                 float* __restrict__ out) {
    __shared__ __align__(16) unsigned short ldsb[NROW * NCC];  // 2880 B

    const int tid = threadIdx.x;
    const int l   = tid & 63;
    const int w   = tid >> 6;       // wave 0..3
    const int h   = w & 1;          // phase-half: p' = 4h + pp
    const int oh  = w >> 1;         // o-half
    const int i   = blockIdx.x;     // output row 0..127
    const int b   = blockIdx.y;     // batch 0..7

    const int lk   = l & 15;        // A-operand m index / B,D o index
    const int g    = (l >> 4) & 1;  // tj half for A
    const int hi32 = l >> 5;        // ti parity within chunk for A
    const int g2   = l >> 4;        // quad 0..3
    const int o    = oh * 16 + lk;

    // ---- B fragments: Bk[k=ti*16+tj][o], zeros for ti>8 or tj>8 (once per block)
    short8 Bf[5];
#pragma unroll
    for (int ch = 0; ch < 5; ++ch) {
        const int ti  = 2 * ch + (g2 >> 1);
        const int tj0 = (g2 & 1) * 8;
        unsigned int pk[4];
#pragma unroll
        for (int ee = 0; ee < 4; ++ee) {
            int tj_a = tj0 + 2 * ee, tj_b = tj_a + 1;
            float va = (ti <= 8 && tj_a <= 8) ? kern[o * 1296 + ti * 9 + tj_a] : 0.f;
            float vb = (ti <= 8 && tj_b <= 8) ? kern[o * 1296 + ti * 9 + tj_b] : 0.f;
            pk[ee] = (unsigned int)f2bf(va) | ((unsigned int)f2bf(vb) << 16);
        }
        uint4v bv; bv.x = pk[0]; bv.y = pk[1]; bv.z = pk[2]; bv.w = pk[3];
        Bf[ch] = __builtin_bit_cast(short8, bv);
    }

    float4v acc[4];
#pragma unroll
    for (int pp = 0; pp < 4; ++pp) acc[pp] = (float4v){0.f, 0.f, 0.f, 0.f};

    for (int c = 0; c < 16; ++c) {
        __syncthreads();  // protect LDS from previous channel's readers
        // ---- stage 10 x 144 bf16, column-reversed, circular wrap
        const float* xp = x + (((size_t)(b * 16 + c)) << 14);
        for (int s = tid; s < NROW * (NCC / 2); s += 256) {   // 720 slots
            int rr = s / (NCC / 2);
            int cc = (s - rr * (NCC / 2)) * 2;
            int xrow = (i - 4 + rr) & 127;
            int c0 = (132 - cc + 256) & 127;
            int c1 = (131 - cc + 256) & 127;
            float v0 = xp[(xrow << 7) + c0];
            float v1 = xp[(xrow << 7) + c1];
            unsigned int pk2 = (unsigned int)f2bf(v0) | ((unsigned int)f2bf(v1) << 16);
            *(unsigned int*)&ldsb[rr * NCC + cc] = pk2;
        }
        __syncthreads();

        float4v D[4];
#pragma unroll
        for (int pp = 0; pp < 4; ++pp) D[pp] = (float4v){0.f, 0.f, 0.f, 0.f};

#pragma unroll
        for (int ch = 0; ch < 5; ++ch) {
            const int ti = 2 * ch + hi32;
            const int r  = 9 - ti;
            // 32 B wide window: 16 taps for this (row, ti), 16B-aligned
            const char* base = (const char*)ldsb + (r * 288 + 240 - 16 * lk + 16 * g);
            uint4v w0 = *(const uint4v*)base;
            uint4v w1 = *(const uint4v*)(base + 16);
            unsigned int wnd[8] = {w0.x, w0.y, w0.z, w0.w, w1.x, w1.y, w1.z, w1.w};
            if (h == 0) {               // phases 0..3 -> byte offsets 14,12,10,8
                MFMA_PHASE(3, 1, D[0]);
                MFMA_PHASE(3, 0, D[1]);
                MFMA_PHASE(2, 1, D[2]);
                MFMA_PHASE(2, 0, D[3]);
            } else {                    // phases 4..7 -> byte offsets 6,4,2,0
                MFMA_PHASE(1, 1, D[0]);
                MFMA_PHASE(1, 0, D[1]);
                MFMA_PHASE(0, 1, D[2]);
                MFMA_PHASE(0, 0, D[3]);
            }
        }
#pragma unroll
        for (int pp = 0; pp < 4; ++pp)
#pragma unroll
            for (int e = 0; e < 4; ++e) acc[pp][e] += fabsf(D[pp][e]);
    }

    // ---- epilogue: lane holds o = oh*16+lk, pixels j = 32*g2 + 8*e + p'
    float* ob = out + ((((size_t)(b * 32 + o)) * 128 + i) << 7);
#pragma unroll
    for (int pp = 0; pp < 4; ++pp) {
        const int pprime = 4 * h + pp;
#pragma unroll
        for (int e = 0; e < 4; ++e)
            ob[32 * g2 + 8 * e + pprime] = acc[pp][e];
    }
}

extern "C" void kernel_launch(void* const* d_in, const int* in_sizes, int n_in,
                              void* d_out, int out_size, void* d_ws, size_t ws_size,
                              hipStream_t stream) {
    const float* x = (const float*)d_in[0];      // [8,16,128,128]
    const float* kern = (const float*)d_in[1];   // [32,16,9,9]
    float* out = (float*)d_out;                  // [8,32,128,128]
    dim3 block(256);
    dim3 grid(128, 8);   // one block per (output row, batch); writes all 32 o
    hipLaunchKernelGGL(optical_conv_69698729279498, grid, block, 0, stream,
                       x, kern, out);
}